// Round 6
// baseline (623.236 us; speedup 1.0000x reference)
//
#include <hip/hip_runtime.h>
#include <cstddef>
#include <cstdint>

#define GAMMA_F 0.99f
#define OMG_F   0.01f      // 1 - gamma
#define EPS_F   1e-5f
#define KN 8192
#define DD 256
#define NN 32768           // B*T

// output layout (float offsets)
#define OFF_ZQ     0
#define OFF_COMMIT 8388608
#define OFF_IDX    8388609
#define OFF_EMB    8421377
#define OFF_MT     10518529
#define OFF_NT     12615681

typedef _Float16 half8 __attribute__((ext_vector_type(8)));
typedef _Float16 half4 __attribute__((ext_vector_type(4)));
typedef float    f32x4 __attribute__((ext_vector_type(4)));
typedef unsigned long long u64;

// ---------------------------------------------------------------------------
// async 16B global->LDS (DMA: lane i -> lds_base + i*16; base wave-uniform,
// global address must be 16B aligned)
__device__ __forceinline__ void gload16(const void* g, void* l) {
    __builtin_amdgcn_global_load_lds(
        (const __attribute__((address_space(1))) unsigned int*)g,
        (__attribute__((address_space(3))) unsigned int*)l, 16, 0, 0);
}

// sortable pack: (monotone f32 bits << 32) | idx  -> u64 min == (dist, idx) min
__device__ __forceinline__ u64 packdi(float dist, int n) {
    unsigned u = __float_as_uint(dist);
    u ^= (unsigned)((int)u >> 31) | 0x80000000u;
    return ((u64)u << 32) | (unsigned)n;
}

// ---------------------------------------------------------------------------
// fp32 -> f16 (RNE), vectorized (for ze)
__global__ __launch_bounds__(256) void conv_hi_kernel(
    const float* __restrict__ x, _Float16* __restrict__ hi) {
    const size_t i0 = ((size_t)blockIdx.x * 256 + threadIdx.x) * 4;
    const float4 v = *(const float4*)(x + i0);
    half4 h;
    h[0] = (_Float16)v.x; h[1] = (_Float16)v.y;
    h[2] = (_Float16)v.z; h[3] = (_Float16)v.w;
    *(half4*)(hi + i0) = h;
}

// ---------------------------------------------------------------------------
// fused: W row -> f16 copy + ||w||^2. One wave per code row.
__global__ __launch_bounds__(64) void convw_wsq_kernel(
    const float* __restrict__ W, _Float16* __restrict__ wh,
    float* __restrict__ wsq) {
    const int k = blockIdx.x;
    const int lane = threadIdx.x;
    const float4 v = *(const float4*)(W + (size_t)k * DD + lane * 4);
    half4 h;
    h[0] = (_Float16)v.x; h[1] = (_Float16)v.y;
    h[2] = (_Float16)v.z; h[3] = (_Float16)v.w;
    *(half4*)(wh + (size_t)k * DD + lane * 4) = h;
    float s = v.x * v.x + v.y * v.y + v.z * v.z + v.w * v.w;
#pragma unroll
    for (int off = 32; off > 0; off >>= 1) s += __shfl_down(s, off, 64);
    if (lane == 0) wsq[k] = s;
}

// ---------------------------------------------------------------------------
// Screening GEMM: single f16 pass, K=256. 128 pts x 128 codes per block.
// Epilogue: shuffle-butterfly top-2 per (point, 64-code wave strip), then a
// tiny 4KB LDS cross-wave merge -> packed (f32 d1, u16 c1, u16 c2) per tile.
__global__ __launch_bounds__(256, 4) void screen_kernel(
    const _Float16* __restrict__ zh, const _Float16* __restrict__ wh,
    const float* __restrict__ wsq, u64* __restrict__ tmin2) {
    __shared__ __align__(16) _Float16 As[128 * 64];   // 16 KB
    __shared__ __align__(16) _Float16 Bs[128 * 64];   // 16 KB
    __shared__ u64 top2[128][4];                      // 4 KB [m][half*2+{0,1}]

    const int tid  = threadIdx.x;
    const int wave = tid >> 6;
    const int lane = tid & 63;
    const int quad = lane >> 4;
    const int col  = lane & 15;
    const int wm = (wave >> 1) * 64;
    const int wn = (wave & 1) * 64;
    const int half = wave & 1;

    const int bm = blockIdx.x >> 6;
    const int bn = blockIdx.x & 63;
    const int m0 = bm * 128;
    const int n0 = bn * 128;

    f32x4 acc[4][4];
#pragma unroll
    for (int i = 0; i < 4; i++)
#pragma unroll
        for (int j = 0; j < 4; j++) acc[i][j] = (f32x4){0.f, 0.f, 0.f, 0.f};

    for (int c = 0; c < 4; ++c) {            // K = 256, 4 chunks of 64
        const int d0 = c * 64;
        __syncthreads();
#pragma unroll
        for (int i = 0; i < 4; ++i) {
            const int clin = (wave * 4 + i) * 64 + lane;   // 0..1023
            const int mrow = clin >> 3;
            const int p = clin & 7;
            const int q = p ^ (mrow & 7);                  // swizzled k-chunk
            gload16(zh + (size_t)(m0 + mrow) * DD + d0 + q * 8,
                    As + (wave * 4 + i) * 512);
            gload16(wh + (size_t)(n0 + mrow) * DD + d0 + q * 8,
                    Bs + (wave * 4 + i) * 512);
        }
        __syncthreads();

#pragma unroll
        for (int kk = 0; kk < 2; ++kk) {
            half8 a[4], b[4];
#pragma unroll
            for (int t = 0; t < 4; ++t) {
                const int mr = wm + t * 16 + col;
                const int nr = wn + t * 16 + col;
                const int cc = kk * 4 + quad;
                a[t] = *(const half8*)(As + mr * 64 + (cc ^ (mr & 7)) * 8);
                b[t] = *(const half8*)(Bs + nr * 64 + (cc ^ (nr & 7)) * 8);
            }
#pragma unroll
            for (int ti = 0; ti < 4; ++ti)
#pragma unroll
                for (int tj = 0; tj < 4; ++tj)
                    acc[ti][tj] = __builtin_amdgcn_mfma_f32_16x16x32_f16(
                        a[ti], b[tj], acc[ti][tj], 0, 0, 0);
        }
    }

    float wq[4];
#pragma unroll
    for (int tj = 0; tj < 4; ++tj) wq[tj] = wsq[n0 + wn + tj * 16 + col];

    // per-row top-2 via shuffle butterfly within each 16-lane quad group
#pragma unroll
    for (int ti = 0; ti < 4; ++ti) {
#pragma unroll
        for (int v = 0; v < 4; ++v) {
            u64 t0 = ~0ull, t1 = ~0ull;
#pragma unroll
            for (int tj = 0; tj < 4; ++tj) {
                const float dist = fmaf(-2.0f, acc[ti][tj][v], wq[tj]);
                const u64 pk = packdi(dist, n0 + wn + tj * 16 + col);
                if (pk < t0) { t1 = t0; t0 = pk; }
                else if (pk < t1) { t1 = pk; }
            }
#pragma unroll
            for (int mk = 1; mk < 16; mk <<= 1) {
                const u64 o0 = __shfl_xor(t0, mk, 64);
                const u64 o1 = __shfl_xor(t1, mk, 64);
                if (o0 < t0) { t1 = t0 < o1 ? t0 : o1; t0 = o0; }
                else         { t1 = t1 < o0 ? t1 : o0; }
            }
            if (col == 0) {
                const int m = wm + ti * 16 + quad * 4 + v;
                top2[m][half * 2 + 0] = t0;
                top2[m][half * 2 + 1] = t1;
            }
        }
    }
    __syncthreads();
    if (tid < 128) {
        const int m = tid;
        const u64 a0 = top2[m][0], a1 = top2[m][1];
        const u64 b0 = top2[m][2], b1 = top2[m][3];
        u64 t0, t1;
        if (a0 < b0) { t0 = a0; t1 = a1 < b0 ? a1 : b0; }
        else         { t0 = b0; t1 = b1 < a0 ? b1 : a0; }
        unsigned u = (unsigned)(t0 >> 32);           // un-monotone -> f32 bits
        u = (u & 0x80000000u) ? (u ^ 0x80000000u) : ~u;
        const u64 ent =
            (u64)u |
            ((u64)((unsigned)t0 & 0xffffu) << 32) |
            ((u64)((unsigned)t1 & 0xffffu) << 48);
        tmin2[(size_t)(m0 + m) * 64 + bn] = ent;
    }
}

// ---------------------------------------------------------------------------
// Per point (one wave, exclusive owner): min over 64 tile records; write all
// codes within window into the point's private slot array. NO atomics.
__global__ __launch_bounds__(256) void compact_kernel(
    const u64* __restrict__ tmin2,
    unsigned* __restrict__ cnt, unsigned* __restrict__ slots) {
    const int tid = threadIdx.x;
    const int lane = tid & 63;
    const int n = blockIdx.x * 4 + (tid >> 6);
    const u64 e = tmin2[(size_t)n * 64 + lane];
    const float d1 = __uint_as_float((unsigned)e);
    float mn = d1;
#pragma unroll
    for (int off = 32; off > 0; off >>= 1)
        mn = fminf(mn, __shfl_xor(mn, off, 64));
    const bool q = d1 <= mn + 1.0f;      // ~30-sigma screen-error window
    const u64 bal = __ballot(q);
    if (q) {
        const int rank = __popcll(bal & ((1ull << lane) - 1ull));
        if (rank < 16) {
            slots[(size_t)n * 32 + 2 * rank + 0] = (unsigned)(e >> 32) & 0xffffu;
            slots[(size_t)n * 32 + 2 * rank + 1] = (unsigned)(e >> 48);
        }
    }
    if (lane == 0) {
        unsigned c = 2u * (unsigned)__popcll(bal);
        cnt[n] = c < 32u ? c : 32u;
    }
}

// ---------------------------------------------------------------------------
// Exact fp32 rescoring: one wave per point; loop over its candidates; write
// the winning index directly. No atomics.
__global__ __launch_bounds__(256) void rescore_kernel(
    const float* __restrict__ ze, const float* __restrict__ W,
    const unsigned* __restrict__ cnt, const unsigned* __restrict__ slots,
    float* __restrict__ idxf) {
    const int tid = threadIdx.x;
    const int lane = tid & 63;
    const int n = blockIdx.x * 4 + (tid >> 6);
    const float4 z = *(const float4*)(ze + (size_t)n * DD + lane * 4);
    const unsigned m = cnt[n];
    u64 best = ~0ull;
    for (unsigned j = 0; j < m; ++j) {
        const unsigned c = slots[(size_t)n * 32 + j];
        const float4 w = *(const float4*)(W + (size_t)c * DD + lane * 4);
        float dot = z.x * w.x + z.y * w.y + z.z * w.z + z.w * w.w;
        float wq  = w.x * w.x + w.y * w.y + w.z * w.z + w.w * w.w;
#pragma unroll
        for (int off = 32; off > 0; off >>= 1) {
            dot += __shfl_xor(dot, off, 64);
            wq  += __shfl_xor(wq, off, 64);
        }
        const float dist = fmaf(-2.0f, dot, wq);
        const u64 pk = packdi(dist, (int)c);
        best = best < pk ? best : pk;
    }
    if (lane == 0) idxf[n] = (float)(unsigned)(best & 0xFFFFFFFFull);
}

// ---------------------------------------------------------------------------
// Gather zq, write zq_st, commit-loss reduce, one-hot scatter (atomics).
__global__ __launch_bounds__(256) void gather_scatter_kernel(
    const float* __restrict__ ze, const float* __restrict__ W,
    const float* __restrict__ idxf, float* __restrict__ zq_out,
    float* __restrict__ commit_acc, float* __restrict__ mt_acc,
    float* __restrict__ nt_acc) {
    const int tid = threadIdx.x;
    const int n = blockIdx.x * 4 + (tid >> 6);
    const int lane = tid & 63;
    const int idx = (int)idxf[n];

    const float4 z = *(const float4*)(ze + (size_t)n * DD + lane * 4);
    const float4 w = *(const float4*)(W + (size_t)idx * DD + lane * 4);

    float4 d, o;
    d.x = w.x - z.x; d.y = w.y - z.y; d.z = w.z - z.z; d.w = w.w - z.w;
    o.x = z.x + d.x; o.y = z.y + d.y; o.z = z.z + d.z; o.w = z.w + d.w;
    *(float4*)(zq_out + (size_t)n * DD + lane * 4) = o;

    float* mp = mt_acc + (size_t)idx * DD + lane * 4;
    atomicAdd(mp + 0, OMG_F * z.x);
    atomicAdd(mp + 1, OMG_F * z.y);
    atomicAdd(mp + 2, OMG_F * z.z);
    atomicAdd(mp + 3, OMG_F * z.w);
    if (lane == 0) atomicAdd(nt_acc + idx, OMG_F);

    float c = d.x * d.x + d.y * d.y + d.z * d.z + d.w * d.w;
#pragma unroll
    for (int off = 32; off > 0; off >>= 1) c += __shfl_down(c, off, 64);

    __shared__ float wsum[4];
    if (lane == 0) wsum[tid >> 6] = c;
    __syncthreads();
    if (tid == 0) {
        const float part = wsum[0] + wsum[1] + wsum[2] + wsum[3];
        atomicAdd(commit_acc, part * (1.0f / 8388608.0f));
    }
}

// ---------------------------------------------------------------------------
__global__ __launch_bounds__(256) void finalize_nt_kernel(
    const float* __restrict__ Nt_in, float* __restrict__ nt_acc) {
    const int k = blockIdx.x * 256 + threadIdx.x;
    nt_acc[k] += GAMMA_F * Nt_in[k];
}

// ---------------------------------------------------------------------------
__global__ __launch_bounds__(256) void final_kernel(
    const float* __restrict__ mt_in, const float* __restrict__ nt_new,
    float* __restrict__ mt_out, float* __restrict__ emb_out) {
    __shared__ float red[256];
    float s = 0.0f;
    for (int i = threadIdx.x; i < KN; i += 256) s += nt_new[i];
    red[threadIdx.x] = s;
    __syncthreads();
    for (int off = 128; off > 0; off >>= 1) {
        if (threadIdx.x < off) red[threadIdx.x] += red[threadIdx.x + off];
        __syncthreads();
    }
    const float n = red[0];

    const size_t i0 = ((size_t)blockIdx.x * 256 + threadIdx.x) * 4;
    const int k = (int)(i0 >> 8);

    const float4 st = *(const float4*)(mt_out + i0);
    const float4 mt = *(const float4*)(mt_in + i0);
    float4 mnew;
    mnew.x = GAMMA_F * mt.x + st.x;
    mnew.y = GAMMA_F * mt.y + st.y;
    mnew.z = GAMMA_F * mt.z + st.z;
    mnew.w = GAMMA_F * mt.w + st.w;
    *(float4*)(mt_out + i0) = mnew;

    const float Nn = (nt_new[k] + EPS_F) * n / (n + (float)KN * EPS_F);
    float4 e;
    e.x = mnew.x / Nn;
    e.y = mnew.y / Nn;
    e.z = mnew.z / Nn;
    e.w = mnew.w / Nn;
    *(float4*)(emb_out + i0) = e;
}

// ---------------------------------------------------------------------------
extern "C" void kernel_launch(void* const* d_in, const int* in_sizes, int n_in,
                              void* d_out, int out_size, void* d_ws, size_t ws_size,
                              hipStream_t stream) {
    const float* ze = (const float*)d_in[0];
    const float* W  = (const float*)d_in[1];
    const float* mt = (const float*)d_in[2];
    const float* Nt = (const float*)d_in[3];

    float* out    = (float*)d_out;
    float* zq_out = out + OFF_ZQ;
    float* commit = out + OFF_COMMIT;
    float* idxf   = out + OFF_IDX;
    float* emb    = out + OFF_EMB;
    float* mtn    = out + OFF_MT;
    float* ntn    = out + OFF_NT;

    // ---- scratch aliases (aligned; all consumed before real outputs written)
    _Float16* zh = (_Float16*)zq_out;                  // NN*DD halfs (16.7 MB)
    u64* tmin2 =                                       // NN*64 u64 (16.78 MB)
        (u64*)(zq_out + (size_t)NN * DD / 2);
    _Float16* wh = (_Float16*)(mtn + 3);               // 16B-aligned
    float* wsqbuf = idxf;                              // KN floats (scratch;
                                                       // overwritten by rescore)
    unsigned* cnt   = (unsigned*)emb;                  // NN u32
    unsigned* slots = (unsigned*)emb + NN;             // NN*32 u32 (4.2 MB)

    // 1) f16 conversions (+ fused ||w||^2 for W)
    conv_hi_kernel<<<(NN * DD / 4) / 256, 256, 0, stream>>>(ze, zh);
    convw_wsq_kernel<<<KN, 64, 0, stream>>>(W, wh, wsqbuf);

    // 2) f16 screening GEMM -> per-(point,tile) top-2 records
    screen_kernel<<<(NN / 128) * (KN / 128), 256, 0, stream>>>(
        zh, wh, wsqbuf, tmin2);

    // 3) window compaction -> per-point candidate slots (atomic-free)
    compact_kernel<<<NN / 4, 256, 0, stream>>>(tmin2, cnt, slots);

    // 4) exact fp32 rescoring -> winning indices written directly
    rescore_kernel<<<NN / 4, 256, 0, stream>>>(ze, W, cnt, slots, idxf);

    // 5) zero accumulation regions (kills wh scratch)
    hipMemsetAsync(commit, 0, sizeof(float), stream);
    hipMemsetAsync(mtn, 0, sizeof(float) * (size_t)KN * DD, stream);
    hipMemsetAsync(ntn, 0, sizeof(float) * KN, stream);

    // 6) gather + commit loss + one-hot scatter (overwrites zh/tmin2)
    gather_scatter_kernel<<<NN / 4, 256, 0, stream>>>(ze, W, idxf, zq_out,
                                                      commit, mtn, ntn);

    // 7) EMA blend for Nt
    finalize_nt_kernel<<<KN / 256, 256, 0, stream>>>(Nt, ntn);

    // 8) mt_new, n, Nn, embedW_new (overwrites cnt/slots scratch)
    final_kernel<<<(KN * DD / 4) / 256, 256, 0, stream>>>(mt, ntn, mtn, emb);
}

// Round 8
// 458.947 us; speedup vs baseline: 1.3580x; 1.3580x over previous
//
#include <hip/hip_runtime.h>
#include <cstddef>
#include <cstdint>

#define GAMMA_F 0.99f
#define OMG_F   0.01f      // 1 - gamma
#define EPS_F   1e-5f
#define KN 8192
#define DD 256
#define NN 32768           // B*T

// output layout (float offsets)
#define OFF_ZQ     0
#define OFF_COMMIT 8388608
#define OFF_IDX    8388609
#define OFF_EMB    8421377
#define OFF_MT     10518529
#define OFF_NT     12615681

typedef _Float16 half8 __attribute__((ext_vector_type(8)));
typedef _Float16 half4 __attribute__((ext_vector_type(4)));
typedef float    f32x4 __attribute__((ext_vector_type(4)));
typedef unsigned long long u64;

// ---------------------------------------------------------------------------
// async 16B global->LDS (DMA: lane i -> lds_base + i*16; base wave-uniform,
// global address must be 16B aligned)
__device__ __forceinline__ void gload16(const void* g, void* l) {
    __builtin_amdgcn_global_load_lds(
        (const __attribute__((address_space(1))) unsigned int*)g,
        (__attribute__((address_space(3))) unsigned int*)l, 16, 0, 0);
}

// sortable pack for exact fp32 rescoring (dist may be negative)
__device__ __forceinline__ u64 packdi(float dist, int n) {
    unsigned u = __float_as_uint(dist);
    u ^= (unsigned)((int)u >> 31) | 0x80000000u;
    return ((u64)u << 32) | (unsigned)n;
}

// ---------------------------------------------------------------------------
// fp32 -> f16 (RNE), vectorized (for ze)
__global__ __launch_bounds__(256) void conv_hi_kernel(
    const float* __restrict__ x, _Float16* __restrict__ hi) {
    const size_t i0 = ((size_t)blockIdx.x * 256 + threadIdx.x) * 4;
    const float4 v = *(const float4*)(x + i0);
    half4 h;
    h[0] = (_Float16)v.x; h[1] = (_Float16)v.y;
    h[2] = (_Float16)v.z; h[3] = (_Float16)v.w;
    *(half4*)(hi + i0) = h;
}

// ---------------------------------------------------------------------------
// fused: W row -> f16 copy + ||w||^2. One wave per code row.
__global__ __launch_bounds__(64) void convw_wsq_kernel(
    const float* __restrict__ W, _Float16* __restrict__ wh,
    float* __restrict__ wsq) {
    const int k = blockIdx.x;
    const int lane = threadIdx.x;
    const float4 v = *(const float4*)(W + (size_t)k * DD + lane * 4);
    half4 h;
    h[0] = (_Float16)v.x; h[1] = (_Float16)v.y;
    h[2] = (_Float16)v.z; h[3] = (_Float16)v.w;
    *(half4*)(wh + (size_t)k * DD + lane * 4) = h;
    float s = v.x * v.x + v.y * v.y + v.z * v.z + v.w * v.w;
#pragma unroll
    for (int off = 32; off > 0; off >>= 1) s += __shfl_down(s, off, 64);
    if (lane == 0) wsq[k] = s;
}

// ---------------------------------------------------------------------------
// Screening GEMM, f16, K=256. Block = 128 points x 128 codes, 4 waves (2x2).
// MFMA operands SWAPPED: A=codes, B=points -> C[row=code][col=point], so each
// lane holds 16 code-dists (registers) for one point. Top-2 per (point,
// 128-code tile) runs on u32-packed (dist+4096, low7=code) values:
// 16 reg inserts + 2 shfl merge steps + tiny LDS cross-half merge.
__global__ __launch_bounds__(256, 4) void screen_kernel(
    const _Float16* __restrict__ zh, const _Float16* __restrict__ wh,
    const float* __restrict__ wsq, u64* __restrict__ tmin2) {
    __shared__ __align__(16) _Float16 As[128 * 64];   // points tile, 16 KB
    __shared__ __align__(16) _Float16 Bs[128 * 64];   // codes tile, 16 KB
    __shared__ __align__(16) u64 top2[128][2];        // [point][code-half]

    const int tid  = threadIdx.x;
    const int wave = tid >> 6;
    const int lane = tid & 63;
    const int quad = lane >> 4;
    const int col  = lane & 15;
    const int ph = wave & 1;        // point half of the block tile
    const int ch = wave >> 1;       // code half
    const int pw = ph * 64;
    const int cw = ch * 64;

    const int bm = blockIdx.x >> 6;     // point-block
    const int bn = blockIdx.x & 63;     // code-block
    const int m0 = bm * 128;
    const int n0 = bn * 128;

    f32x4 acc[4][4];                // [ci (codes)][pj (points)]
#pragma unroll
    for (int i = 0; i < 4; i++)
#pragma unroll
        for (int j = 0; j < 4; j++) acc[i][j] = (f32x4){0.f, 0.f, 0.f, 0.f};

    for (int c = 0; c < 4; ++c) {            // K = 256, 4 chunks of 64
        const int d0 = c * 64;
        __syncthreads();
#pragma unroll
        for (int i = 0; i < 4; ++i) {
            const int clin = (wave * 4 + i) * 64 + lane;   // 0..1023
            const int mrow = clin >> 3;
            const int p = clin & 7;
            const int q = p ^ (mrow & 7);                  // swizzled k-chunk
            gload16(zh + (size_t)(m0 + mrow) * DD + d0 + q * 8,
                    As + (wave * 4 + i) * 512);
            gload16(wh + (size_t)(n0 + mrow) * DD + d0 + q * 8,
                    Bs + (wave * 4 + i) * 512);
        }
        __syncthreads();

#pragma unroll
        for (int kk = 0; kk < 2; ++kk) {
            half8 a[4], b[4];
#pragma unroll
            for (int t = 0; t < 4; ++t) {
                const int cr = cw + t * 16 + col;   // code row
                const int pr = pw + t * 16 + col;   // point row
                const int cc = kk * 4 + quad;
                a[t] = *(const half8*)(Bs + cr * 64 + (cc ^ (cr & 7)) * 8);
                b[t] = *(const half8*)(As + pr * 64 + (cc ^ (pr & 7)) * 8);
            }
#pragma unroll
            for (int ci = 0; ci < 4; ++ci)
#pragma unroll
                for (int pj = 0; pj < 4; ++pj)
                    acc[ci][pj] = __builtin_amdgcn_mfma_f32_16x16x32_f16(
                        a[ci], b[pj], acc[ci][pj], 0, 0, 0);
        }
    }

    // wq[ci][v] = wsq[code] + 4096 (offset makes all dists positive -> raw
    // f32 bits monotone as u32)
    float wq[4][4];
#pragma unroll
    for (int ci = 0; ci < 4; ++ci) {
        const float4 t = *(const float4*)(wsq + n0 + cw + ci * 16 + quad * 4);
        wq[ci][0] = t.x + 4096.f; wq[ci][1] = t.y + 4096.f;
        wq[ci][2] = t.z + 4096.f; wq[ci][3] = t.w + 4096.f;
    }
    const unsigned base7 = (unsigned)(cw + quad * 4);

#pragma unroll
    for (int pj = 0; pj < 4; ++pj) {
        unsigned t0 = 0xFFFFFFFFu, t1 = 0xFFFFFFFFu;
#pragma unroll
        for (int ci = 0; ci < 4; ++ci)
#pragma unroll
            for (int v = 0; v < 4; ++v) {
                const float dist = fmaf(-2.0f, acc[ci][pj][v], wq[ci][v]);
                const unsigned x = (__float_as_uint(dist) & ~127u) |
                                   (base7 + ci * 16 + v);
                const unsigned mx = t0 > x ? t0 : x;
                t0 = t0 < x ? t0 : x;
                t1 = t1 < mx ? t1 : mx;
            }
        // merge sorted pairs across the 4 quads (same point col)
#pragma unroll
        for (int mk = 16; mk < 64; mk <<= 1) {
            const unsigned o0 = __shfl_xor(t0, mk, 64);
            const unsigned o1 = __shfl_xor(t1, mk, 64);
            const unsigned lo = t0 < o0 ? t0 : o0;
            const unsigned hi = t0 < o0 ? o0 : t0;
            const unsigned mn = t1 < o1 ? t1 : o1;
            t0 = lo;
            t1 = hi < mn ? hi : mn;
        }
        if (quad == 0)
            top2[pw + pj * 16 + col][ch] = ((u64)t1 << 32) | t0;
    }
    __syncthreads();
    if (tid < 128) {
        const u64 e0 = top2[tid][0], e1 = top2[tid][1];
        const unsigned a0 = (unsigned)e0, a1 = (unsigned)(e0 >> 32);
        const unsigned b0 = (unsigned)e1, b1 = (unsigned)(e1 >> 32);
        const unsigned t0 = a0 < b0 ? a0 : b0;
        const unsigned hi = a0 < b0 ? b0 : a0;
        const unsigned mn = a1 < b1 ? a1 : b1;
        const unsigned t1 = hi < mn ? hi : mn;
        const unsigned c1 = n0 + (t0 & 127u);
        const unsigned c2 = n0 + (t1 & 127u);
        const u64 ent = (u64)(t0 & ~127u) | ((u64)c1 << 32) | ((u64)c2 << 48);
        // transposed layout [tile][point] -> fully coalesced 1KB block write
        tmin2[(size_t)bn * NN + m0 + tid] = ent;
    }
}

// ---------------------------------------------------------------------------
// Per point (one wave): min over 64 tile records; write window candidates to
// the point's private slots. Also zeroes mt/nt/commit accumulators (fused
// memsets; GUARDED to exactly KN*DD floats).
__global__ __launch_bounds__(256) void compact_kernel(
    const u64* __restrict__ tmin2,
    unsigned* __restrict__ cnt, unsigned* __restrict__ slots,
    float* __restrict__ mt_zero, float* __restrict__ nt_zero,
    float* __restrict__ commit_zero) {
    const int tid = threadIdx.x;
    const int gid = blockIdx.x * 256 + tid;
    if (gid < KN * DD / 4)
        *(float4*)(mt_zero + (size_t)gid * 4) = (float4){0.f, 0.f, 0.f, 0.f};
    if (gid < KN) nt_zero[gid] = 0.f;
    if (gid == 0) *commit_zero = 0.f;

    const int lane = tid & 63;
    const int n = blockIdx.x * 4 + (tid >> 6);
    const u64 e = tmin2[(size_t)lane * NN + n];
    const float d1 = __uint_as_float((unsigned)e);   // offset by +4096, quantized
    float mn = d1;
#pragma unroll
    for (int off = 32; off > 0; off >>= 1)
        mn = fminf(mn, __shfl_xor(mn, off, 64));
    const bool q = d1 <= mn + 1.0f;      // >=25-sigma window incl. quantization
    const u64 bal = __ballot(q);
    if (q) {
        const int rank = __popcll(bal & ((1ull << lane) - 1ull));
        if (rank < 16) {
            slots[(size_t)n * 32 + 2 * rank + 0] = (unsigned)(e >> 32) & 0xffffu;
            slots[(size_t)n * 32 + 2 * rank + 1] = (unsigned)(e >> 48);
        }
    }
    if (lane == 0) {
        unsigned c = 2u * (unsigned)__popcll(bal);
        cnt[n] = c < 32u ? c : 32u;
    }
}

// ---------------------------------------------------------------------------
// Fused: exact fp32 rescore of candidates -> winning index; then gather zq,
// write zq_st, commit-loss reduce, one-hot scatter. One wave per point.
__global__ __launch_bounds__(256) void rescore_gather_kernel(
    const float* __restrict__ ze, const float* __restrict__ W,
    const unsigned* __restrict__ cnt, const unsigned* __restrict__ slots,
    float* __restrict__ idxf, float* __restrict__ zq_out,
    float* __restrict__ commit_acc, float* __restrict__ mt_acc,
    float* __restrict__ nt_acc) {
    const int tid = threadIdx.x;
    const int lane = tid & 63;
    const int n = blockIdx.x * 4 + (tid >> 6);
    const float4 z = *(const float4*)(ze + (size_t)n * DD + lane * 4);
    const unsigned m = cnt[n];
    u64 best = ~0ull;
    for (unsigned j = 0; j < m; ++j) {
        const unsigned c = slots[(size_t)n * 32 + j];
        const float4 w = *(const float4*)(W + (size_t)c * DD + lane * 4);
        float dot = z.x * w.x + z.y * w.y + z.z * w.z + z.w * w.w;
        float wq  = w.x * w.x + w.y * w.y + w.z * w.z + w.w * w.w;
#pragma unroll
        for (int off = 32; off > 0; off >>= 1) {
            dot += __shfl_xor(dot, off, 64);
            wq  += __shfl_xor(wq, off, 64);
        }
        const float dist = fmaf(-2.0f, dot, wq);
        const u64 pk = packdi(dist, (int)c);
        best = best < pk ? best : pk;
    }
    const int idx = (int)(unsigned)(best & 0xFFFFFFFFull);  // wave-uniform
    if (lane == 0) idxf[n] = (float)idx;

    const float4 w = *(const float4*)(W + (size_t)idx * DD + lane * 4);
    float4 d, o;
    d.x = w.x - z.x; d.y = w.y - z.y; d.z = w.z - z.z; d.w = w.w - z.w;
    o.x = z.x + d.x; o.y = z.y + d.y; o.z = z.z + d.z; o.w = z.w + d.w;
    *(float4*)(zq_out + (size_t)n * DD + lane * 4) = o;

    float* mp = mt_acc + (size_t)idx * DD + lane * 4;
    atomicAdd(mp + 0, OMG_F * z.x);
    atomicAdd(mp + 1, OMG_F * z.y);
    atomicAdd(mp + 2, OMG_F * z.z);
    atomicAdd(mp + 3, OMG_F * z.w);
    if (lane == 0) atomicAdd(nt_acc + idx, OMG_F);

    float c = d.x * d.x + d.y * d.y + d.z * d.z + d.w * d.w;
#pragma unroll
    for (int off = 32; off > 0; off >>= 1) c += __shfl_down(c, off, 64);

    __shared__ float wsum[4];
    if (lane == 0) wsum[tid >> 6] = c;
    __syncthreads();
    if (tid == 0) {
        const float part = wsum[0] + wsum[1] + wsum[2] + wsum[3];
        atomicAdd(commit_acc, part * (1.0f / 8388608.0f));
    }
}

// ---------------------------------------------------------------------------
__global__ __launch_bounds__(256) void finalize_nt_kernel(
    const float* __restrict__ Nt_in, float* __restrict__ nt_acc) {
    const int k = blockIdx.x * 256 + threadIdx.x;
    nt_acc[k] += GAMMA_F * Nt_in[k];
}

// ---------------------------------------------------------------------------
__global__ __launch_bounds__(256) void final_kernel(
    const float* __restrict__ mt_in, const float* __restrict__ nt_new,
    float* __restrict__ mt_out, float* __restrict__ emb_out) {
    __shared__ float red[256];
    float s = 0.0f;
    for (int i = threadIdx.x; i < KN; i += 256) s += nt_new[i];
    red[threadIdx.x] = s;
    __syncthreads();
    for (int off = 128; off > 0; off >>= 1) {
        if (threadIdx.x < off) red[threadIdx.x] += red[threadIdx.x + off];
        __syncthreads();
    }
    const float n = red[0];

    const size_t i0 = ((size_t)blockIdx.x * 256 + threadIdx.x) * 4;
    const int k = (int)(i0 >> 8);

    const float4 st = *(const float4*)(mt_out + i0);
    const float4 mt = *(const float4*)(mt_in + i0);
    float4 mnew;
    mnew.x = GAMMA_F * mt.x + st.x;
    mnew.y = GAMMA_F * mt.y + st.y;
    mnew.z = GAMMA_F * mt.z + st.z;
    mnew.w = GAMMA_F * mt.w + st.w;
    *(float4*)(mt_out + i0) = mnew;

    const float Nn = (nt_new[k] + EPS_F) * n / (n + (float)KN * EPS_F);
    float4 e;
    e.x = mnew.x / Nn;
    e.y = mnew.y / Nn;
    e.z = mnew.z / Nn;
    e.w = mnew.w / Nn;
    *(float4*)(emb_out + i0) = e;
}

// ---------------------------------------------------------------------------
extern "C" void kernel_launch(void* const* d_in, const int* in_sizes, int n_in,
                              void* d_out, int out_size, void* d_ws, size_t ws_size,
                              hipStream_t stream) {
    const float* ze = (const float*)d_in[0];
    const float* W  = (const float*)d_in[1];
    const float* mt = (const float*)d_in[2];
    const float* Nt = (const float*)d_in[3];

    float* out    = (float*)d_out;
    float* zq_out = out + OFF_ZQ;
    float* commit = out + OFF_COMMIT;
    float* idxf   = out + OFF_IDX;
    float* emb    = out + OFF_EMB;
    float* mtn    = out + OFF_MT;
    float* ntn    = out + OFF_NT;

    // ---- scratch aliases (aligned; all consumed before real outputs written)
    _Float16* zh = (_Float16*)zq_out;                  // NN*DD halfs (16.7 MB)
    u64* tmin2 =                                       // [64 tiles][NN points]
        (u64*)(zq_out + (size_t)NN * DD / 2);
    _Float16* wh = (_Float16*)(mtn + 3);               // 16B-aligned
    float* wsqbuf = idxf + 3;                          // 16B-aligned scratch in
                                                       // idx region (KN floats)
    unsigned* cnt   = (unsigned*)emb;                  // NN u32
    unsigned* slots = (unsigned*)emb + NN;             // NN*32 u32 (4.2 MB)

    // 1) f16 conversions (+ fused ||w||^2 for W)
    conv_hi_kernel<<<(NN * DD / 4) / 256, 256, 0, stream>>>(ze, zh);
    convw_wsq_kernel<<<KN, 64, 0, stream>>>(W, wh, wsqbuf);

    // 2) f16 screening GEMM -> per-(point,tile) top-2 records
    screen_kernel<<<(NN / 128) * (KN / 128), 256, 0, stream>>>(
        zh, wh, wsqbuf, tmin2);

    // 3) window compaction -> per-point slots; fused zeroing of mt/nt/commit
    compact_kernel<<<NN / 4, 256, 0, stream>>>(tmin2, cnt, slots,
                                               mtn, ntn, commit);

    // 4) exact fp32 rescore + gather + commit + one-hot scatter (fused;
    //    overwrites wsqbuf scratch via idxf writes — wsq already consumed)
    rescore_gather_kernel<<<NN / 4, 256, 0, stream>>>(
        ze, W, cnt, slots, idxf, zq_out, commit, mtn, ntn);

    // 5) EMA blend for Nt
    finalize_nt_kernel<<<KN / 256, 256, 0, stream>>>(Nt, ntn);

    // 6) mt_new, n, Nn, embedW_new (overwrites cnt/slots scratch)
    final_kernel<<<(KN * DD / 4) / 256, 256, 0, stream>>>(mt, ntn, mtn, emb);
}